// Round 9
// baseline (551.852 us; speedup 1.0000x reference)
//
#include <hip/hip_runtime.h>
#include <hip/hip_bf16.h>

typedef unsigned short u16;
typedef unsigned int u32;
typedef float floatx4 __attribute__((ext_vector_type(4)));
typedef _Float16 f16x8 __attribute__((ext_vector_type(8)));

#define NN 8192
#define DD 512
#define NPARTS 8
#define JCHUNK 1024       // NN / NPARTS
#define RB_PER_PART 128   // row-blocks (64 Q rows each) per part

__device__ __forceinline__ u16 f2h(float f) {
    _Float16 h = (_Float16)f;                 // RNE
    return __builtin_bit_cast(u16, h);
}
__device__ __forceinline__ float h2f(u16 u) {
    _Float16 h = __builtin_bit_cast(_Float16, u);
    return (float)h;
}

// async 16B-per-lane global->LDS DMA (wave-uniform LDS base + lane*16).
__device__ __forceinline__ void async16(const u16* g, u16* l) {
    __builtin_amdgcn_global_load_lds(
        (const __attribute__((address_space(1))) u32*)g,
        (__attribute__((address_space(3))) u32*)l, 16, 0, 0);
}

// Pipeline barrier: wait only until <=4 vm ops outstanding (the newest DMA
// group stays in flight). NOT __syncthreads (which drains vmcnt(0)).
#define PIPE_BAR() asm volatile("s_waitcnt vmcnt(4)\n\ts_barrier" ::: "memory")
// Compiler-only fence: keep Q-loads ordered before the phase's DMA issue.
#define CFENCE()   asm volatile("" ::: "memory")

// ---------------------------------------------------------------------------
// Projection GEMM, fp16 single-term (fp32 accumulate).
// z=0: Q = x1@q (row-major fp16), z=1: K = x2@k, z=2: VT = (x1@v)^T
// ---------------------------------------------------------------------------
__global__ __launch_bounds__(256, 2)
void proj_kernel(const float* __restrict__ x1, const float* __restrict__ x2,
                 const float* __restrict__ qw, const float* __restrict__ kw,
                 const float* __restrict__ vw,
                 u16* __restrict__ Qf, u16* __restrict__ Kf, u16* __restrict__ VT)
{
    const int which = blockIdx.z;
    const float* A = (which == 1) ? x2 : x1;
    const float* W = (which == 0) ? qw : (which == 1 ? kw : vw);

    __shared__ u16 Ash[128 * 40];   // [m][k]
    __shared__ u16 Wsh[128 * 40];   // [n][k] (W transposed)

    const int tid  = threadIdx.x;
    const int lane = tid & 63;
    const int wave = tid >> 6;
    const int l15  = lane & 15;
    const int quad = lane >> 4;
    const int wm   = (wave & 1) * 64;
    const int wn   = (wave >> 1) * 64;
    const int m0   = blockIdx.x * 128;
    const int n0   = blockIdx.y * 128;

    floatx4 acc[4][4] = {};

    for (int k0 = 0; k0 < DD; k0 += 32) {
        __syncthreads();
        {   // Stage A tile: 128 x 32 fp32 -> fp16 [m][k]
            const int cg = (tid & 7) * 4;
            for (int i = 0; i < 4; i++) {
                const int row = (tid >> 3) + i * 32;
                float4 f = *(const float4*)&A[(size_t)(m0 + row) * DD + k0 + cg];
                uint2 p;
                p.x = ((unsigned)f2h(f.y) << 16) | f2h(f.x);
                p.y = ((unsigned)f2h(f.w) << 16) | f2h(f.z);
                *(uint2*)&Ash[row * 40 + cg] = p;
            }
        }
        {   // Stage W tile: 32(k) x 128(n) -> fp16 [n][k]
            const int kr = tid & 31;
            const int g  = tid >> 5;
            for (int i = 0; i < 4; i++) {
                const int n = (g + i * 8) * 4;
                float4 f = *(const float4*)&W[(size_t)(k0 + kr) * DD + n0 + n];
                Wsh[(n + 0) * 40 + kr] = f2h(f.x);
                Wsh[(n + 1) * 40 + kr] = f2h(f.y);
                Wsh[(n + 2) * 40 + kr] = f2h(f.z);
                Wsh[(n + 3) * 40 + kr] = f2h(f.w);
            }
        }
        __syncthreads();

        f16x8 af[4], bf[4];
        for (int mi = 0; mi < 4; mi++)
            af[mi] = *(const f16x8*)&Ash[(wm + mi * 16 + l15) * 40 + quad * 8];
        for (int ni = 0; ni < 4; ni++)
            bf[ni] = *(const f16x8*)&Wsh[(wn + ni * 16 + l15) * 40 + quad * 8];
        for (int mi = 0; mi < 4; mi++)
            for (int ni = 0; ni < 4; ni++)
                acc[mi][ni] = __builtin_amdgcn_mfma_f32_16x16x32_f16(
                    af[mi], bf[ni], acc[mi][ni], 0, 0, 0);
    }

    for (int mi = 0; mi < 4; mi++)
        for (int ni = 0; ni < 4; ni++)
            for (int r = 0; r < 4; r++) {
                const int row = m0 + wm + mi * 16 + quad * 4 + r;
                const int col = n0 + wn + ni * 16 + l15;
                const u16 hv = f2h(acc[mi][ni][r]);
                if (which == 0)      Qf[(size_t)row * DD + col] = hv;
                else if (which == 1) Kf[(size_t)row * DD + col] = hv;
                else                 VT[(size_t)col * NN + row] = hv;
            }
}

// ---------------------------------------------------------------------------
// Flash attention partials — depth-2 async pipeline + VGPR-freed ILP:
//  * Q-frags not resident (64 VGPRs freed): reloaded per QK quarter from
//    global (L1-hot 16KB/wave), issued BEFORE the phase's DMA group so the
//    Q-use vmcnt(<=4) leaves the newest stage group in flight.
//  * Explicit 1-group-ahead register double-buffer of B-frags in qkQ/pvQ.
// ---------------------------------------------------------------------------
__global__ __launch_bounds__(256, 2)
void attn_kernel(const u16* __restrict__ Qf, const u16* __restrict__ Kf,
                 const u16* __restrict__ VT,
                 u16* __restrict__ Opart, float* __restrict__ Mp,
                 float* __restrict__ Lp, int* __restrict__ cnt)
{
    const int tid  = threadIdx.x;
    const int lane = tid & 63;
    const int wave = tid >> 6;
    const int l15  = lane & 15;
    const int quad = lane >> 4;

    __shared__ u16 KV[4][8192];         // 4 x 16KB ring
    __shared__ u16 Ps[4][16 * 68];      // per-wave P transpose
    __shared__ int sPart, sRb;

    // ---- claim work item pinned to this block's physical XCD ----
    if (tid == 0) {
        u32 xcd;
        asm volatile("s_getreg_b32 %0, hwreg(HW_REG_XCC_ID)" : "=s"(xcd));
        xcd &= 7;
        int part = -1, rb = 0;
        for (int t = 0; t < 8; t++) {
            const int p = (xcd + t) & 7;
            const int idx = atomicAdd(&cnt[p], 1);
            if (idx < RB_PER_PART) { part = p; rb = idx; break; }
        }
        sPart = part; sRb = rb;
    }
    __syncthreads();
    const int part = sPart;
    const int rb   = sRb;
    if (part < 0) return;               // unreachable (pigeonhole)

    const int q0 = rb * 64 + wave * 16;
    const u16* qbase = &Qf[(size_t)(q0 + l15) * DD + quad * 8];

    floatx4 o[32] = {};
    float m_run[4], l_run[4];
    for (int r = 0; r < 4; r++) { m_run[r] = -1e30f; l_run[r] = 0.f; }

    const int j_begin = part * JCHUNK;
    const int j_end   = j_begin + JCHUNK;

    // --- staging: 4 async16/wave per call = 16KB/block ---
    const int krow4  = lane >> 4;        // K: row-sub 0..3
    const int kpos16 = lane & 15;        // K: chunk pos in row (of 16)
    const int vrs    = lane >> 3;        // V: row-sub 0..7
    const int vch    = (lane & 7) ^ vrs; // V: swizzled source chunk

    auto stageKq = [&](int dq, int j0, int rg) {
        for (int c = 0; c < 4; c++) {
            const int jj  = wave * 16 + c * 4;
            const int row = jj + krow4;
            const int sch = kpos16 ^ (row & 7);
            async16(&Kf[(size_t)(j0 + row) * DD + dq * 128 + sch * 8],
                    &KV[rg][jj * 128]);
        }
    };
    auto stageVq = [&](int dq, int j0, int rg) {
        for (int c = 0; c < 4; c++) {
            const int dl = wave * 32 + c * 8;
            async16(&VT[(size_t)(dq * 128 + dl + vrs) * NN + j0 + vch * 8],
                    &KV[rg][dl * 64]);
        }
    };

    // Q quarter fetch (global, L1-hot): issued before the phase's DMA group
    f16x8 qq[4];
    auto qfetch = [&](int dq) {
        for (int k8 = 0; k8 < 4; k8++)
            qq[k8] = *(const f16x8*)&qbase[(dq * 4 + k8) * 32];
    };

    // QK quarter: 16 ds_read_b128 + 16 MFMA, 1-group-ahead reg double-buffer
    auto qkQ = [&](int rg, floatx4* s) {
        f16x8 b[2][4];
        auto loadg = [&](int k8, f16x8* dst) {
            for (int nt = 0; nt < 4; nt++) {
                const int row = nt * 16 + l15;
                const int ch  = (k8 * 4 + quad) ^ (l15 & 7);
                dst[nt] = *(const f16x8*)&KV[rg][row * 128 + ch * 8];
            }
        };
        loadg(0, b[0]);
        for (int k8 = 0; k8 < 4; k8++) {
            if (k8 < 3) loadg(k8 + 1, b[(k8 + 1) & 1]);
            for (int nt = 0; nt < 4; nt++)
                s[nt] = __builtin_amdgcn_mfma_f32_16x16x32_f16(
                    qq[k8], b[k8 & 1][nt], s[nt], 0, 0, 0);
        }
    };
    // PV quarter: 16 ds_read_b128 + 16 MFMA, grouped 2 o-tiles (4 reads/group)
    auto pvQ = [&](int rg, int dq, f16x8* pf) {
        f16x8 b[2][4];
        auto loadg = [&](int g, f16x8* dst) {
            for (int i = 0; i < 2; i++) {
                const int row = (g * 2 + i) * 16 + l15;
                const int c0  = quad ^ (l15 & 7);
                const int c1  = (4 + quad) ^ (l15 & 7);
                dst[i * 2 + 0] = *(const f16x8*)&KV[rg][row * 64 + c0 * 8];
                dst[i * 2 + 1] = *(const f16x8*)&KV[rg][row * 64 + c1 * 8];
            }
        };
        loadg(0, b[0]);
        for (int g = 0; g < 4; g++) {
            if (g < 3) loadg(g + 1, b[(g + 1) & 1]);
            for (int i = 0; i < 2; i++) {
                const int ot = dq * 8 + g * 2 + i;
                o[ot] = __builtin_amdgcn_mfma_f32_16x16x32_f16(pf[0], b[g & 1][i * 2 + 0], o[ot], 0, 0, 0);
                o[ot] = __builtin_amdgcn_mfma_f32_16x16x32_f16(pf[1], b[g & 1][i * 2 + 1], o[ot], 0, 0, 0);
            }
        }
    };

    // preamble: stage K d0->R0, K d1->R1; wait d0 group only
    stageKq(0, j_begin, 0);
    stageKq(1, j_begin, 1);
    PIPE_BAR();

    for (int j0 = j_begin; j0 < j_end; j0 += 64) {
        const int jn = (j0 + 64 < j_end) ? j0 + 64 : j_begin;  // wrap: uniform count
        floatx4 s[4] = {};

        qfetch(0); CFENCE(); stageKq(2, j0, 2); qkQ(0, s); PIPE_BAR();  // p0
        qfetch(1); CFENCE(); stageKq(3, j0, 3); qkQ(1, s); PIPE_BAR();  // p1
        qfetch(2); CFENCE(); stageVq(0, j0, 0); qkQ(2, s); PIPE_BAR();  // p2
        qfetch(3); CFENCE(); stageVq(1, j0, 1); qkQ(3, s);              // p3

        // ---- leaky_relu + online softmax (unchanged math order) ----
        for (int nt = 0; nt < 4; nt++)
            for (int r = 0; r < 4; r++) {
                float x = s[nt][r];
                s[nt][r] = x >= 0.f ? x : 0.01f * x;
            }
        float mt[4];
        for (int r = 0; r < 4; r++)
            mt[r] = fmaxf(fmaxf(s[0][r], s[1][r]), fmaxf(s[2][r], s[3][r]));
        for (int off = 1; off < 16; off <<= 1)
            for (int r = 0; r < 4; r++)
                mt[r] = fmaxf(mt[r], __shfl_xor(mt[r], off));

        float alpha[4];
        for (int r = 0; r < 4; r++) {
            const float mnew = fmaxf(m_run[r], mt[r]);
            alpha[r] = __expf(m_run[r] - mnew);
            m_run[r] = mnew;
        }
        float ls[4] = {0.f, 0.f, 0.f, 0.f};
        u16 pv[4][4];
        for (int nt = 0; nt < 4; nt++)
            for (int r = 0; r < 4; r++) {
                const float p = __expf(s[nt][r] - m_run[r]);
                ls[r] += p;
                pv[nt][r] = f2h(p);
            }
        for (int off = 1; off < 16; off <<= 1)
            for (int r = 0; r < 4; r++)
                ls[r] += __shfl_xor(ls[r], off);
        for (int r = 0; r < 4; r++)
            l_run[r] = l_run[r] * alpha[r] + ls[r];
        const bool need = (alpha[0] != 1.f) | (alpha[1] != 1.f) |
                          (alpha[2] != 1.f) | (alpha[3] != 1.f);
        if (__any(need))
            for (int i = 0; i < 32; i++)
                for (int r = 0; r < 4; r++)
                    o[i][r] *= alpha[r];

        // P: C-layout -> A-layout via per-wave LDS (same-wave, lgkm only)
        for (int nt = 0; nt < 4; nt++)
            for (int r = 0; r < 4; r++)
                Ps[wave][(quad * 4 + r) * 68 + nt * 16 + l15] = pv[nt][r];
        asm volatile("s_waitcnt lgkmcnt(0)" ::: "memory");
        f16x8 pf[2];
        for (int ks = 0; ks < 2; ks++)
            pf[ks] = *(const f16x8*)&Ps[wave][l15 * 68 + ks * 32 + quad * 8];
        PIPE_BAR();                                                     // end p3

        stageVq(2, j0, 2); pvQ(0, 0, pf); PIPE_BAR();                   // p4
        stageVq(3, j0, 3); pvQ(1, 1, pf); PIPE_BAR();                   // p5
        stageKq(0, jn, 0); pvQ(2, 2, pf); PIPE_BAR();                   // p6
        stageKq(1, jn, 1); pvQ(3, 3, pf); PIPE_BAR();                   // p7
    }

    // drain remaining DMA before epilogue / endpgm
    asm volatile("s_waitcnt vmcnt(0)" ::: "memory");

    // ---- write partials (fp16 un-normalized O + fp32 m,l) ----
    for (int i = 0; i < 32; i++)
        for (int r = 0; r < 4; r++) {
            const int row = q0 + quad * 4 + r;
            const int col = i * 16 + l15;
            Opart[((size_t)part * NN + row) * DD + col] = f2h(o[i][r]);
        }
    if (l15 == 0)
        for (int r = 0; r < 4; r++) {
            const int row = q0 + quad * 4 + r;
            Mp[part * NN + row] = m_run[r];
            Lp[part * NN + row] = l_run[r];
        }
}

// ---------------------------------------------------------------------------
// Combine NPARTS j-partials: out = sum_p w_p O_p / sum_p w_p l_p
// ---------------------------------------------------------------------------
__global__ __launch_bounds__(256)
void combine_kernel(const u16* __restrict__ Opart, const float* __restrict__ Mp,
                    const float* __restrict__ Lp, float* __restrict__ out)
{
    const int row = blockIdx.x;
    const int tid = threadIdx.x;
    float m[NPARTS], l[NPARTS];
    float M = -1e30f;
    for (int p = 0; p < NPARTS; p++) {
        m[p] = Mp[p * NN + row];
        l[p] = Lp[p * NN + row];
        M = fmaxf(M, m[p]);
    }
    float w[NPARTS], L = 0.f;
    for (int p = 0; p < NPARTS; p++) { w[p] = __expf(m[p] - M); L += w[p] * l[p]; }
    const float inv = 1.f / L;
    for (int d = tid; d < DD; d += 256) {
        float acc = 0.f;
        for (int p = 0; p < NPARTS; p++)
            acc += w[p] * h2f(Opart[((size_t)p * NN + row) * DD + d]);
        out[(size_t)row * DD + d] = acc * inv;
    }
}

// ---------------------------------------------------------------------------
extern "C" void kernel_launch(void* const* d_in, const int* in_sizes, int n_in,
                              void* d_out, int out_size, void* d_ws, size_t ws_size,
                              hipStream_t stream)
{
    const float* x1 = (const float*)d_in[0];
    const float* x2 = (const float*)d_in[1];
    const float* qw = (const float*)d_in[2];
    const float* kw = (const float*)d_in[3];
    const float* vw = (const float*)d_in[4];
    float* out = (float*)d_out;

    // workspace: Qf|Kf|VT (8MB each fp16) | Opart 64MB fp16 | Mp | Lp | cnt[8]
    u16* Qf = (u16*)d_ws;
    u16* Kf = Qf + (size_t)NN * DD;
    u16* VT = Kf + (size_t)NN * DD;
    u16* Opart = VT + (size_t)NN * DD;
    float* Mp = (float*)(Opart + (size_t)NPARTS * NN * DD);
    float* Lp = Mp + NPARTS * NN;
    int* cnt = (int*)(Lp + NPARTS * NN);

    hipMemsetAsync(cnt, 0, NPARTS * sizeof(int), stream);
    proj_kernel<<<dim3(64, 4, 3), 256, 0, stream>>>(x1, x2, qw, kw, vw, Qf, Kf, VT);
    attn_kernel<<<dim3(RB_PER_PART * NPARTS), 256, 0, stream>>>(Qf, Kf, VT, Opart, Mp, Lp, cnt);
    combine_kernel<<<NN, 256, 0, stream>>>(Opart, Mp, Lp, out);
}

// Round 10
// 543.452 us; speedup vs baseline: 1.0155x; 1.0155x over previous
//
#include <hip/hip_runtime.h>
#include <hip/hip_bf16.h>

typedef unsigned short u16;
typedef unsigned int u32;
typedef float floatx4 __attribute__((ext_vector_type(4)));
typedef _Float16 f16x8 __attribute__((ext_vector_type(8)));

#define NN 8192
#define DD 512
#define NPARTS 8
#define JCHUNK 1024       // NN / NPARTS
#define RB_PER_PART 171   // 48-row blocks per part: 171*48 >= 8192

__device__ __forceinline__ u16 f2h(float f) {
    _Float16 h = (_Float16)f;                 // RNE
    return __builtin_bit_cast(u16, h);
}
__device__ __forceinline__ float h2f(u16 u) {
    _Float16 h = __builtin_bit_cast(_Float16, u);
    return (float)h;
}

// async 16B-per-lane global->LDS DMA (wave-uniform LDS base + lane*16).
__device__ __forceinline__ void async16(const u16* g, u16* l) {
    __builtin_amdgcn_global_load_lds(
        (const __attribute__((address_space(1))) u32*)g,
        (__attribute__((address_space(3))) u32*)l, 16, 0, 0);
}

// ---------------------------------------------------------------------------
// Projection GEMM, fp16 single-term (fp32 accumulate).  (unchanged)
// z=0: Q = x1@q (row-major fp16), z=1: K = x2@k, z=2: VT = (x1@v)^T
// ---------------------------------------------------------------------------
__global__ __launch_bounds__(256, 2)
void proj_kernel(const float* __restrict__ x1, const float* __restrict__ x2,
                 const float* __restrict__ qw, const float* __restrict__ kw,
                 const float* __restrict__ vw,
                 u16* __restrict__ Qf, u16* __restrict__ Kf, u16* __restrict__ VT)
{
    const int which = blockIdx.z;
    const float* A = (which == 1) ? x2 : x1;
    const float* W = (which == 0) ? qw : (which == 1 ? kw : vw);

    __shared__ u16 Ash[128 * 40];   // [m][k]
    __shared__ u16 Wsh[128 * 40];   // [n][k] (W transposed)

    const int tid  = threadIdx.x;
    const int lane = tid & 63;
    const int wave = tid >> 6;
    const int l15  = lane & 15;
    const int quad = lane >> 4;
    const int wm   = (wave & 1) * 64;
    const int wn   = (wave >> 1) * 64;
    const int m0   = blockIdx.x * 128;
    const int n0   = blockIdx.y * 128;

    floatx4 acc[4][4] = {};

    for (int k0 = 0; k0 < DD; k0 += 32) {
        __syncthreads();
        {   // Stage A tile: 128 x 32 fp32 -> fp16 [m][k]
            const int cg = (tid & 7) * 4;
            for (int i = 0; i < 4; i++) {
                const int row = (tid >> 3) + i * 32;
                float4 f = *(const float4*)&A[(size_t)(m0 + row) * DD + k0 + cg];
                uint2 p;
                p.x = ((unsigned)f2h(f.y) << 16) | f2h(f.x);
                p.y = ((unsigned)f2h(f.w) << 16) | f2h(f.z);
                *(uint2*)&Ash[row * 40 + cg] = p;
            }
        }
        {   // Stage W tile: 32(k) x 128(n) -> fp16 [n][k]
            const int kr = tid & 31;
            const int g  = tid >> 5;
            for (int i = 0; i < 4; i++) {
                const int n = (g + i * 8) * 4;
                float4 f = *(const float4*)&W[(size_t)(k0 + kr) * DD + n0 + n];
                Wsh[(n + 0) * 40 + kr] = f2h(f.x);
                Wsh[(n + 1) * 40 + kr] = f2h(f.y);
                Wsh[(n + 2) * 40 + kr] = f2h(f.z);
                Wsh[(n + 3) * 40 + kr] = f2h(f.w);
            }
        }
        __syncthreads();

        f16x8 af[4], bf[4];
        for (int mi = 0; mi < 4; mi++)
            af[mi] = *(const f16x8*)&Ash[(wm + mi * 16 + l15) * 40 + quad * 8];
        for (int ni = 0; ni < 4; ni++)
            bf[ni] = *(const f16x8*)&Wsh[(wn + ni * 16 + l15) * 40 + quad * 8];
        for (int mi = 0; mi < 4; mi++)
            for (int ni = 0; ni < 4; ni++)
                acc[mi][ni] = __builtin_amdgcn_mfma_f32_16x16x32_f16(
                    af[mi], bf[ni], acc[mi][ni], 0, 0, 0);
    }

    for (int mi = 0; mi < 4; mi++)
        for (int ni = 0; ni < 4; ni++)
            for (int r = 0; r < 4; r++) {
                const int row = m0 + wm + mi * 16 + quad * 4 + r;
                const int col = n0 + wn + ni * 16 + l15;
                const u16 hv = f2h(acc[mi][ni][r]);
                if (which == 0)      Qf[(size_t)row * DD + col] = hv;
                else if (which == 1) Kf[(size_t)row * DD + col] = hv;
                else                 VT[(size_t)col * NN + row] = hv;
            }
}

// ---------------------------------------------------------------------------
// Flash attention partials — PRODUCER/CONSUMER wave specialization.
// Block = 4 waves: wave 3 = DMA producer (issues all 16 global_load_lds per
// phase, waits vmcnt(16) pre-barrier -> newest group stays in flight); waves
// 0-2 = consumers (16 Q-rows each, Q register-resident, NO in-loop VMEM ->
// their barrier has NO vmcnt wait; DMA latency never blocks compute).
// At barrier-release the next region is guaranteed landed (producer drained
// it). Ring/swizzle/schedule identical to R7 (4x16KB, depth-2, 8 phases).
// XCD-pinned claim: 171 items x 8 queues = 1368 blocks exactly.
// ---------------------------------------------------------------------------
__global__ __launch_bounds__(256, 2)
void attn_kernel(const u16* __restrict__ Qf, const u16* __restrict__ Kf,
                 const u16* __restrict__ VT,
                 u16* __restrict__ Opart, float* __restrict__ Mp,
                 float* __restrict__ Lp, int* __restrict__ cnt)
{
    const int tid  = threadIdx.x;
    const int lane = tid & 63;
    const int wave = tid >> 6;
    const int l15  = lane & 15;
    const int quad = lane >> 4;

    __shared__ u16 KV[4][8192];         // 4 x 16KB ring
    __shared__ u16 Ps[3][16 * 68];      // per-consumer-wave P transpose
    __shared__ int sPart, sRb;

    // ---- claim work item pinned to this block's physical XCD ----
    if (tid == 0) {
        u32 xcd;
        asm volatile("s_getreg_b32 %0, hwreg(HW_REG_XCC_ID)" : "=s"(xcd));
        xcd &= 7;
        int part = -1, rb = 0;
        for (int t = 0; t < 8; t++) {
            const int p = (xcd + t) & 7;
            const int idx = atomicAdd(&cnt[p], 1);
            if (idx < RB_PER_PART) { part = p; rb = idx; break; }
        }
        sPart = part; sRb = rb;
    }
    __syncthreads();
    const int part = sPart;
    const int rb   = sRb;
    if (part < 0) return;               // unreachable (pigeonhole)

    const bool prod = (wave == 3);

    // consumer Q rows (48 per block; clamp overflow wave of last block —
    // duplicate compute/writes of identical values, benign)
    int q0 = rb * 48 + wave * 16;
    if (q0 > NN - 16) q0 = NN - 16;

    // Q register-resident for consumers (16 A-frags, full D=512)
    f16x8 qf[16];
    if (!prod)
        for (int kk = 0; kk < 16; kk++)
            qf[kk] = *(const f16x8*)&Qf[(size_t)(q0 + l15) * DD + kk * 32 + quad * 8];

    floatx4 o[32] = {};
    float m_run[4], l_run[4];
    for (int r = 0; r < 4; r++) { m_run[r] = -1e30f; l_run[r] = 0.f; }

    const int j_begin = part * JCHUNK;
    const int j_end   = j_begin + JCHUNK;

    // --- producer staging: 16 async16 per phase = whole 16KB region ---
    const int krow4  = lane >> 4;        // K: row-sub 0..3
    const int kpos16 = lane & 15;        // K: chunk pos in row
    const int vrs    = lane >> 3;        // V: row-sub 0..7
    const int vch    = (lane & 7) ^ vrs; // V: swizzled source chunk

    auto stageKq = [&](int dq, int j0, int rg) {
        for (int c = 0; c < 16; c++) {
            const int jj  = c * 4;
            const int row = jj + krow4;
            const int sch = kpos16 ^ (row & 7);
            async16(&Kf[(size_t)(j0 + row) * DD + dq * 128 + sch * 8],
                    &KV[rg][jj * 128]);
        }
    };
    auto stageVq = [&](int dq, int j0, int rg) {
        for (int c = 0; c < 16; c++) {
            const int dl = c * 8;
            async16(&VT[(size_t)(dq * 128 + dl + vrs) * NN + j0 + vch * 8],
                    &KV[rg][dl * 64]);
        }
    };

    // --- consumer compute: QK / PV quarters (16 ds_read_b128 + 16 MFMA) ---
    auto qkQ = [&](int rg, int dq, floatx4* s) {
        for (int k8 = 0; k8 < 4; k8++)
            for (int nt = 0; nt < 4; nt++) {
                const int row = nt * 16 + l15;
                const int ch  = (k8 * 4 + quad) ^ (l15 & 7);
                f16x8 b = *(const f16x8*)&KV[rg][row * 128 + ch * 8];
                s[nt] = __builtin_amdgcn_mfma_f32_16x16x32_f16(qf[dq * 4 + k8], b, s[nt], 0, 0, 0);
            }
    };
    auto pvQ = [&](int rg, int dq, f16x8* pf) {
        for (int t = 0; t < 8; t++) {
            const int row = t * 16 + l15;
            const int c0  = quad ^ (l15 & 7);
            const int c1  = (4 + quad) ^ (l15 & 7);
            f16x8 b0 = *(const f16x8*)&KV[rg][row * 64 + c0 * 8];
            f16x8 b1 = *(const f16x8*)&KV[rg][row * 64 + c1 * 8];
            o[dq * 8 + t] = __builtin_amdgcn_mfma_f32_16x16x32_f16(pf[0], b0, o[dq * 8 + t], 0, 0, 0);
            o[dq * 8 + t] = __builtin_amdgcn_mfma_f32_16x16x32_f16(pf[1], b1, o[dq * 8 + t], 0, 0, 0);
        }
    };

    // Phase barrier: producer drains all but its newest 16-op DMA group;
    // consumers do a BARE barrier (no vmcnt — they have no in-loop VMEM).
    auto pbar = [&]() {
        if (prod) asm volatile("s_waitcnt vmcnt(16)" ::: "memory");
        asm volatile("s_barrier" ::: "memory");
    };

    // preamble: producer stages K d0->R0, K d1->R1
    if (prod) { stageKq(0, j_begin, 0); stageKq(1, j_begin, 1); }
    pbar();

    for (int j0 = j_begin; j0 < j_end; j0 += 64) {
        const int jn = (j0 + 64 < j_end) ? j0 + 64 : j_begin;  // wrap: uniform count
        floatx4 s[4] = {};
        f16x8 pf[2];

        if (prod) stageKq(2, j0, 2); else qkQ(0, 0, s);  pbar();   // p0
        if (prod) stageKq(3, j0, 3); else qkQ(1, 1, s);  pbar();   // p1
        if (prod) stageVq(0, j0, 0); else qkQ(2, 2, s);  pbar();   // p2

        // p3: producer stages V d1; consumers finish QK + softmax + P
        if (prod) {
            stageVq(1, j0, 1);
        } else {
            qkQ(3, 3, s);

            for (int nt = 0; nt < 4; nt++)
                for (int r = 0; r < 4; r++) {
                    float x = s[nt][r];
                    s[nt][r] = x >= 0.f ? x : 0.01f * x;
                }
            float mt[4];
            for (int r = 0; r < 4; r++)
                mt[r] = fmaxf(fmaxf(s[0][r], s[1][r]), fmaxf(s[2][r], s[3][r]));
            for (int off = 1; off < 16; off <<= 1)
                for (int r = 0; r < 4; r++)
                    mt[r] = fmaxf(mt[r], __shfl_xor(mt[r], off));

            float alpha[4];
            for (int r = 0; r < 4; r++) {
                const float mnew = fmaxf(m_run[r], mt[r]);
                alpha[r] = __expf(m_run[r] - mnew);
                m_run[r] = mnew;
            }
            float ls[4] = {0.f, 0.f, 0.f, 0.f};
            u16 pv[4][4];
            for (int nt = 0; nt < 4; nt++)
                for (int r = 0; r < 4; r++) {
                    const float p = __expf(s[nt][r] - m_run[r]);
                    ls[r] += p;
                    pv[nt][r] = f2h(p);
                }
            for (int off = 1; off < 16; off <<= 1)
                for (int r = 0; r < 4; r++)
                    ls[r] += __shfl_xor(ls[r], off);
            for (int r = 0; r < 4; r++)
                l_run[r] = l_run[r] * alpha[r] + ls[r];
            const bool need = (alpha[0] != 1.f) | (alpha[1] != 1.f) |
                              (alpha[2] != 1.f) | (alpha[3] != 1.f);
            if (__any(need))
                for (int i = 0; i < 32; i++)
                    for (int r = 0; r < 4; r++)
                        o[i][r] *= alpha[r];

            // P: C-layout -> A-layout via per-wave LDS (same-wave, lgkm only)
            for (int nt = 0; nt < 4; nt++)
                for (int r = 0; r < 4; r++)
                    Ps[wave][(quad * 4 + r) * 68 + nt * 16 + l15] = pv[nt][r];
            asm volatile("s_waitcnt lgkmcnt(0)" ::: "memory");
            for (int ks = 0; ks < 2; ks++)
                pf[ks] = *(const f16x8*)&Ps[wave][l15 * 68 + ks * 32 + quad * 8];
        }
        pbar();                                                     // end p3

        if (prod) stageVq(2, j0, 2); else pvQ(0, 0, pf);  pbar();   // p4
        if (prod) stageVq(3, j0, 3); else pvQ(1, 1, pf);  pbar();   // p5
        if (prod) stageKq(0, jn, 0); else pvQ(2, 2, pf);  pbar();   // p6
        if (prod) stageKq(1, jn, 1); else pvQ(3, 3, pf);  pbar();   // p7
    }

    // drain remaining DMA before epilogue / endpgm
    asm volatile("s_waitcnt vmcnt(0)" ::: "memory");

    // ---- consumer epilogue: fp16 un-normalized O + fp32 m,l ----
    if (!prod) {
        for (int i = 0; i < 32; i++)
            for (int r = 0; r < 4; r++) {
                const int row = q0 + quad * 4 + r;
                const int col = i * 16 + l15;
                Opart[((size_t)part * NN + row) * DD + col] = f2h(o[i][r]);
            }
        if (l15 == 0)
            for (int r = 0; r < 4; r++) {
                const int row = q0 + quad * 4 + r;
                Mp[part * NN + row] = m_run[r];
                Lp[part * NN + row] = l_run[r];
            }
    }
}

// ---------------------------------------------------------------------------
// Combine NPARTS j-partials: out = sum_p w_p O_p / sum_p w_p l_p
// ---------------------------------------------------------------------------
__global__ __launch_bounds__(256)
void combine_kernel(const u16* __restrict__ Opart, const float* __restrict__ Mp,
                    const float* __restrict__ Lp, float* __restrict__ out)
{
    const int row = blockIdx.x;
    const int tid = threadIdx.x;
    float m[NPARTS], l[NPARTS];
    float M = -1e30f;
    for (int p = 0; p < NPARTS; p++) {
        m[p] = Mp[p * NN + row];
        l[p] = Lp[p * NN + row];
        M = fmaxf(M, m[p]);
    }
    float w[NPARTS], L = 0.f;
    for (int p = 0; p < NPARTS; p++) { w[p] = __expf(m[p] - M); L += w[p] * l[p]; }
    const float inv = 1.f / L;
    for (int d = tid; d < DD; d += 256) {
        float acc = 0.f;
        for (int p = 0; p < NPARTS; p++)
            acc += w[p] * h2f(Opart[((size_t)p * NN + row) * DD + d]);
        out[(size_t)row * DD + d] = acc * inv;
    }
}

// ---------------------------------------------------------------------------
extern "C" void kernel_launch(void* const* d_in, const int* in_sizes, int n_in,
                              void* d_out, int out_size, void* d_ws, size_t ws_size,
                              hipStream_t stream)
{
    const float* x1 = (const float*)d_in[0];
    const float* x2 = (const float*)d_in[1];
    const float* qw = (const float*)d_in[2];
    const float* kw = (const float*)d_in[3];
    const float* vw = (const float*)d_in[4];
    float* out = (float*)d_out;

    // workspace: Qf|Kf|VT (8MB each fp16) | Opart 64MB fp16 | Mp | Lp | cnt[8]
    u16* Qf = (u16*)d_ws;
    u16* Kf = Qf + (size_t)NN * DD;
    u16* VT = Kf + (size_t)NN * DD;
    u16* Opart = VT + (size_t)NN * DD;
    float* Mp = (float*)(Opart + (size_t)NPARTS * NN * DD);
    float* Lp = Mp + NPARTS * NN;
    int* cnt = (int*)(Lp + NPARTS * NN);

    hipMemsetAsync(cnt, 0, NPARTS * sizeof(int), stream);
    proj_kernel<<<dim3(64, 4, 3), 256, 0, stream>>>(x1, x2, qw, kw, vw, Qf, Kf, VT);
    attn_kernel<<<dim3(RB_PER_PART * NPARTS), 256, 0, stream>>>(Qf, Kf, VT, Opart, Mp, Lp, cnt);
    combine_kernel<<<NN, 256, 0, stream>>>(Opart, Mp, Lp, out);
}